// Round 4
// baseline (2858.760 us; speedup 1.0000x reference)
//
#include <hip/hip_runtime.h>

#define Bsz 128
#define Tn  1024
#define Dn  256
#define Hn  256

typedef _Float16 f16;
typedef _Float16 f16x4 __attribute__((ext_vector_type(4)));
typedef _Float16 f16x8 __attribute__((ext_vector_type(8)));
typedef float f32x4 __attribute__((ext_vector_type(4)));

// Exact tanh: 1 - 2/(e^{2x}+1) via v_exp_f32 (exp2). Saturates to +/-1 for
// large |x| (exp2 -> inf or 0), no NaN for finite x. err ~1e-6.
__device__ __forceinline__ float tanh_fast(float x) {
    float e = __builtin_amdgcn_exp2f(x * 2.88539008177793f);  // e^{2x}
    return 1.0f - 2.0f * __builtin_amdgcn_rcpf(e + 1.0f);
}

// Raw barrier: LDS-visibility only (lgkmcnt). Avoids the compiler's
// s_waitcnt vmcnt(0) drain before s_barrier so global prefetches/stores
// stay in flight across steps. Safe: every pre[] element is touched by
// exactly one (wave,lane); per-lane load->use->store ordering is enforced
// by the dependency waitcnt at the use.
__device__ __forceinline__ void wg_barrier() {
    asm volatile("s_waitcnt lgkmcnt(0)\n\ts_barrier" ::: "memory");
}

// ---------------------------------------------------------------------------
// K1: pre[t][b][j] = x[b][t][:] @ W^T + bias   (fp32 in, fp32 out, fp16 MFMA)
// grid = B*T/64 wgs, 256 thr. Each wg: 64 M-rows x 256 cols.
// ---------------------------------------------------------------------------
__global__ __launch_bounds__(256, 1) void k_xproj(
    const float* __restrict__ x, const float* __restrict__ W,
    const float* __restrict__ bias, float* __restrict__ pre)
{
    __shared__ __align__(16) f16 atile[64][264];
    const int tid = threadIdx.x;
    const int n0 = blockIdx.x * 64;

    #pragma unroll
    for (int i = 0; i < 16; i++) {
        int f = i * 256 + tid;                 // 0..4095 float4-slots
        int row = f >> 6, c4 = f & 63;
        float4 v = *(const float4*)(x + (n0 + row) * Dn + c4 * 4);
        f16x4 t = { (f16)v.x, (f16)v.y, (f16)v.z, (f16)v.w };
        *(f16x4*)(&atile[row][c4 * 4]) = t;
    }
    __syncthreads();

    const int lane = tid & 63, l15 = lane & 15, quad = lane >> 4;
    const int colbase = (tid >> 6) * 64;

    f16x8 bw[4][8];
    float bi[4];
    #pragma unroll
    for (int jn = 0; jn < 4; jn++) {
        int col = colbase + jn * 16 + l15;
        bi[jn] = bias[col];
        #pragma unroll
        for (int kk = 0; kk < 8; kk++) {
            #pragma unroll
            for (int j = 0; j < 8; j++)
                bw[jn][kk][j] = (f16)W[col * Dn + kk * 32 + quad * 8 + j];
        }
    }

    const int b  = n0 >> 10;
    const int tb = n0 & 1023;

    #pragma unroll 1
    for (int mt = 0; mt < 4; mt++) {
        f32x4 acc[4];
        #pragma unroll
        for (int jn = 0; jn < 4; jn++) acc[jn] = (f32x4){0.f, 0.f, 0.f, 0.f};
        #pragma unroll
        for (int kk = 0; kk < 8; kk++) {
            f16x8 a = *(const f16x8*)(&atile[mt * 16 + l15][kk * 32 + quad * 8]);
            #pragma unroll
            for (int jn = 0; jn < 4; jn++)
                acc[jn] = __builtin_amdgcn_mfma_f32_16x16x32_f16(a, bw[jn][kk], acc[jn], 0, 0, 0);
        }
        #pragma unroll
        for (int jn = 0; jn < 4; jn++) {
            int col = colbase + jn * 16 + l15;
            #pragma unroll
            for (int r = 0; r < 4; r++) {
                int t = tb + mt * 16 + quad * 4 + r;
                pre[t * (Bsz * Hn) + b * Hn + col] = acc[jn][r] + bi[jn];
            }
        }
    }
}

// ---------------------------------------------------------------------------
// K2: layer-1 recurrence fused with layer-2 input projection.
//   for t: h1 = tanh(pre1[t] + h1 @ Whh0^T)          (bias0 folded in pre1)
//          pre[t] <- h1 @ Wxh1^T + b1                (in-place overwrite)
// grid = 8 wgs (16 batch rows each), 256 thr (4 waves, 64 cols each).
// ---------------------------------------------------------------------------
__global__ __launch_bounds__(256, 1) void k_rec1(
    const float* __restrict__ Whh, const float* __restrict__ Wxh,
    const float* __restrict__ bias1, float* __restrict__ pre)
{
    __shared__ __align__(16) f16 hbuf[2][16][264];
    const int tid = threadIdx.x;
    const int lane = tid & 63, l15 = lane & 15, quad = lane >> 4;
    const int colbase = (tid >> 6) * 64;

    for (int i = tid; i < 2 * 16 * 264; i += 256) ((f16*)hbuf)[i] = (f16)0.0f;

    f16x8 wh[4][8], wx[4][8];
    float bi[4];
    #pragma unroll
    for (int jn = 0; jn < 4; jn++) {
        int col = colbase + jn * 16 + l15;
        bi[jn] = bias1[col];
        #pragma unroll
        for (int kk = 0; kk < 8; kk++) {
            #pragma unroll
            for (int j = 0; j < 8; j++) {
                wh[jn][kk][j] = (f16)Whh[col * Hn + kk * 32 + quad * 8 + j];
                wx[jn][kk][j] = (f16)Wxh[col * Hn + kk * 32 + quad * 8 + j];
            }
        }
    }

    const int bg = blockIdx.x * 16 + quad * 4;  // global batch row base (C-layout rows)
    float pA[16], pB[16];
    #pragma unroll
    for (int jn = 0; jn < 4; jn++)
        #pragma unroll
        for (int r = 0; r < 4; r++) {
            pA[jn * 4 + r] = pre[0 * Bsz * Hn + (bg + r) * Hn + colbase + jn * 16 + l15];
            pB[jn * 4 + r] = pre[1 * Bsz * Hn + (bg + r) * Hn + colbase + jn * 16 + l15];
        }
    __syncthreads();

#define REC1_STEP(SRC, DST, PR, TT) { \
    f32x4 acc[4]; \
    _Pragma("unroll") for (int jn = 0; jn < 4; jn++) acc[jn] = (f32x4){0.f,0.f,0.f,0.f}; \
    _Pragma("unroll") for (int kk = 0; kk < 8; kk++) { \
        f16x8 a = *(const f16x8*)(&SRC[l15][kk * 32 + quad * 8]); \
        _Pragma("unroll") for (int jn = 0; jn < 4; jn++) \
            acc[jn] = __builtin_amdgcn_mfma_f32_16x16x32_f16(a, wh[jn][kk], acc[jn], 0, 0, 0); \
    } \
    _Pragma("unroll") for (int jn = 0; jn < 4; jn++) \
        _Pragma("unroll") for (int r = 0; r < 4; r++) { \
            float v = acc[jn][r] + PR[jn * 4 + r]; \
            DST[quad * 4 + r][colbase + jn * 16 + l15] = (f16)tanh_fast(v); \
        } \
    { int tf = ((TT) + 2 < Tn) ? (TT) + 2 : Tn - 1; \
      _Pragma("unroll") for (int jn = 0; jn < 4; jn++) \
          _Pragma("unroll") for (int r = 0; r < 4; r++) \
              PR[jn * 4 + r] = pre[tf * Bsz * Hn + (bg + r) * Hn + colbase + jn * 16 + l15]; } \
    wg_barrier(); \
    f32x4 acc2[4]; \
    _Pragma("unroll") for (int jn = 0; jn < 4; jn++) acc2[jn] = (f32x4){0.f,0.f,0.f,0.f}; \
    _Pragma("unroll") for (int kk = 0; kk < 8; kk++) { \
        f16x8 a = *(const f16x8*)(&DST[l15][kk * 32 + quad * 8]); \
        _Pragma("unroll") for (int jn = 0; jn < 4; jn++) \
            acc2[jn] = __builtin_amdgcn_mfma_f32_16x16x32_f16(a, wx[jn][kk], acc2[jn], 0, 0, 0); \
    } \
    _Pragma("unroll") for (int jn = 0; jn < 4; jn++) \
        _Pragma("unroll") for (int r = 0; r < 4; r++) \
            pre[(TT) * Bsz * Hn + (bg + r) * Hn + colbase + jn * 16 + l15] = \
                acc2[jn][r] + bi[jn]; \
}

    #pragma unroll 1
    for (int tp = 0; tp < Tn / 2; ++tp) {
        const int t0 = tp * 2;
        REC1_STEP(hbuf[0], hbuf[1], pA, t0)
        REC1_STEP(hbuf[1], hbuf[0], pB, (t0 + 1))
    }
#undef REC1_STEP
}

// ---------------------------------------------------------------------------
// K3: layer-2 recurrence + fc head on last step.
//   for t: h2 = tanh(pre2[t] + h2 @ Whh1^T)   (bias1 folded in pre2)
//   out[b][o] = h2_last[b] . fc_w[o] + fc_b[o]     (out is fp32)
// ---------------------------------------------------------------------------
__global__ __launch_bounds__(256, 1) void k_rec2(
    const float* __restrict__ Whh, const float* __restrict__ fcw,
    const float* __restrict__ fcb, const float* __restrict__ pre,
    float* __restrict__ out)
{
    __shared__ __align__(16) f16 hbuf[2][16][264];
    const int tid = threadIdx.x;
    const int lane = tid & 63, l15 = lane & 15, quad = lane >> 4;
    const int colbase = (tid >> 6) * 64;

    for (int i = tid; i < 2 * 16 * 264; i += 256) ((f16*)hbuf)[i] = (f16)0.0f;

    f16x8 wh[4][8];
    #pragma unroll
    for (int jn = 0; jn < 4; jn++) {
        int col = colbase + jn * 16 + l15;
        #pragma unroll
        for (int kk = 0; kk < 8; kk++) {
            #pragma unroll
            for (int j = 0; j < 8; j++)
                wh[jn][kk][j] = (f16)Whh[col * Hn + kk * 32 + quad * 8 + j];
        }
    }

    const int bg = blockIdx.x * 16 + quad * 4;
    float pA[16], pB[16];
    #pragma unroll
    for (int jn = 0; jn < 4; jn++)
        #pragma unroll
        for (int r = 0; r < 4; r++) {
            pA[jn * 4 + r] = pre[0 * Bsz * Hn + (bg + r) * Hn + colbase + jn * 16 + l15];
            pB[jn * 4 + r] = pre[1 * Bsz * Hn + (bg + r) * Hn + colbase + jn * 16 + l15];
        }
    __syncthreads();

#define REC2_STEP(SRC, DST, PR, TT) { \
    f32x4 acc[4]; \
    _Pragma("unroll") for (int jn = 0; jn < 4; jn++) acc[jn] = (f32x4){0.f,0.f,0.f,0.f}; \
    _Pragma("unroll") for (int kk = 0; kk < 8; kk++) { \
        f16x8 a = *(const f16x8*)(&SRC[l15][kk * 32 + quad * 8]); \
        _Pragma("unroll") for (int jn = 0; jn < 4; jn++) \
            acc[jn] = __builtin_amdgcn_mfma_f32_16x16x32_f16(a, wh[jn][kk], acc[jn], 0, 0, 0); \
    } \
    _Pragma("unroll") for (int jn = 0; jn < 4; jn++) \
        _Pragma("unroll") for (int r = 0; r < 4; r++) { \
            float v = acc[jn][r] + PR[jn * 4 + r]; \
            DST[quad * 4 + r][colbase + jn * 16 + l15] = (f16)tanh_fast(v); \
        } \
    { int tf = ((TT) + 2 < Tn) ? (TT) + 2 : Tn - 1; \
      _Pragma("unroll") for (int jn = 0; jn < 4; jn++) \
          _Pragma("unroll") for (int r = 0; r < 4; r++) \
              PR[jn * 4 + r] = pre[tf * Bsz * Hn + (bg + r) * Hn + colbase + jn * 16 + l15]; } \
    wg_barrier(); \
}

    #pragma unroll 1
    for (int tp = 0; tp < Tn / 2; ++tp) {
        const int t0 = tp * 2;
        REC2_STEP(hbuf[0], hbuf[1], pA, t0)
        REC2_STEP(hbuf[1], hbuf[0], pB, (t0 + 1))
    }
#undef REC2_STEP

    // head: h2_last is in hbuf[0] (step 1023 writes hbuf[0]; barrier done).
    const int bl = tid >> 4, o = (tid >> 3) & 1, kc = tid & 7;
    float s = 0.f;
    #pragma unroll
    for (int k = 0; k < 32; k++)
        s += (float)hbuf[0][bl][kc * 32 + k] * fcw[o * Hn + kc * 32 + k];
    s += __shfl_down(s, 4);
    s += __shfl_down(s, 2);
    s += __shfl_down(s, 1);
    if (kc == 0)
        out[(blockIdx.x * 16 + bl) * 2 + o] = s + fcb[o];
}

extern "C" void kernel_launch(void* const* d_in, const int* in_sizes, int n_in,
                              void* d_out, int out_size, void* d_ws, size_t ws_size,
                              hipStream_t stream) {
    const float* x    = (const float*)d_in[0];
    const float* Wxh0 = (const float*)d_in[1];
    const float* Whh0 = (const float*)d_in[2];
    const float* b0   = (const float*)d_in[3];
    const float* Wxh1 = (const float*)d_in[4];
    const float* Whh1 = (const float*)d_in[5];
    const float* b1   = (const float*)d_in[6];
    const float* fcw  = (const float*)d_in[7];
    const float* fcb  = (const float*)d_in[8];
    float* out = (float*)d_out;

    float* pre = (float*)d_ws;  // [T][B][H] fp32 = 128 MiB

    k_xproj<<<dim3(Bsz * Tn / 64), dim3(256), 0, stream>>>(x, Wxh0, b0, pre);
    k_rec1 <<<dim3(Bsz / 16),      dim3(256), 0, stream>>>(Whh0, Wxh1, b1, pre);
    k_rec2 <<<dim3(Bsz / 16),      dim3(256), 0, stream>>>(Whh1, fcw, fcb, pre, out);
}

// Round 5
// 2176.704 us; speedup vs baseline: 1.3133x; 1.3133x over previous
//
#include <hip/hip_runtime.h>

#define Bsz 128
#define Tn  1024
#define Dn  256
#define Hn  256
#define WXS 264   // Wxh1 LDS row stride (f16 elems)
#define HS  264   // h-buffer row stride (f16 elems)

typedef _Float16 f16;
typedef _Float16 f16x4 __attribute__((ext_vector_type(4)));
typedef _Float16 f16x8 __attribute__((ext_vector_type(8)));
typedef float f32x4 __attribute__((ext_vector_type(4)));

// Exact tanh: 1 - 2/(e^{2x}+1) via v_exp_f32. err ~1e-6, saturates correctly.
__device__ __forceinline__ float tanh_fast(float x) {
    float e = __builtin_amdgcn_exp2f(x * 2.88539008177793f);  // e^{2x}
    return 1.0f - 2.0f * __builtin_amdgcn_rcpf(e + 1.0f);
}

// LDS-only barrier (lgkmcnt drain, no vmcnt) so pre1 prefetch loads stay in
// flight across steps. All global loads are consumed by the issuing lane
// (dependency waitcnt at use); kernel has no per-step global stores.
__device__ __forceinline__ void wg_barrier() {
    asm volatile("s_waitcnt lgkmcnt(0)\n\ts_barrier" ::: "memory");
}

// ---------------------------------------------------------------------------
// K1: pre[t][b][j] = x[b][t][:] @ Wxh0^T + b0   (fp32 in/out, f16 MFMA)
// ---------------------------------------------------------------------------
__global__ __launch_bounds__(256, 1) void k_xproj(
    const float* __restrict__ x, const float* __restrict__ W,
    const float* __restrict__ bias, float* __restrict__ pre)
{
    __shared__ __align__(16) f16 atile[64][264];
    const int tid = threadIdx.x;
    const int n0 = blockIdx.x * 64;

    #pragma unroll
    for (int i = 0; i < 16; i++) {
        int f = i * 256 + tid;
        int row = f >> 6, c4 = f & 63;
        float4 v = *(const float4*)(x + (n0 + row) * Dn + c4 * 4);
        f16x4 t = { (f16)v.x, (f16)v.y, (f16)v.z, (f16)v.w };
        *(f16x4*)(&atile[row][c4 * 4]) = t;
    }
    __syncthreads();

    const int lane = tid & 63, l15 = lane & 15, quad = lane >> 4;
    const int colbase = (tid >> 6) * 64;

    f16x8 bw[4][8];
    float bi[4];
    #pragma unroll
    for (int jn = 0; jn < 4; jn++) {
        int col = colbase + jn * 16 + l15;
        bi[jn] = bias[col];
        #pragma unroll
        for (int kk = 0; kk < 8; kk++) {
            #pragma unroll
            for (int j = 0; j < 8; j++)
                bw[jn][kk][j] = (f16)W[col * Dn + kk * 32 + quad * 8 + j];
        }
    }

    const int b  = n0 >> 10;
    const int tb = n0 & 1023;

    #pragma unroll 1
    for (int mt = 0; mt < 4; mt++) {
        f32x4 acc[4];
        #pragma unroll
        for (int jn = 0; jn < 4; jn++) acc[jn] = (f32x4){0.f, 0.f, 0.f, 0.f};
        #pragma unroll
        for (int kk = 0; kk < 8; kk++) {
            f16x8 a = *(const f16x8*)(&atile[mt * 16 + l15][kk * 32 + quad * 8]);
            #pragma unroll
            for (int jn = 0; jn < 4; jn++)
                acc[jn] = __builtin_amdgcn_mfma_f32_16x16x32_f16(a, bw[jn][kk], acc[jn], 0, 0, 0);
        }
        #pragma unroll
        for (int jn = 0; jn < 4; jn++) {
            int col = colbase + jn * 16 + l15;
            #pragma unroll
            for (int r = 0; r < 4; r++) {
                int t = tb + mt * 16 + quad * 4 + r;
                pre[t * (Bsz * Hn) + b * Hn + col] = acc[jn][r] + bi[jn];
            }
        }
    }
}

// ---------------------------------------------------------------------------
// K2 (fused): both recurrences + head, one WG per 16 batch rows.
//   per step t:
//     h1 = tanh(pre1[t] + h1 @ Whh0^T)                  [phase A]
//     h2 = tanh(b1 + h1 @ Wxh1^T + h2 @ Whh1^T)         [phase BC, pre2 in regs]
//   out[b][:] = h2[1023] @ fc_w^T + fc_b
// 8 WGs x 512 thr (8 waves, 32 cols each; 2 waves/SIMD for latency hiding).
// Whh0/Whh1 fragments in registers; Wxh1 staged in LDS (f16).
// ---------------------------------------------------------------------------
__global__ __launch_bounds__(512, 2) void k_fused(
    const float* __restrict__ Whh0, const float* __restrict__ Wxh1,
    const float* __restrict__ Whh1, const float* __restrict__ b1v,
    const float* __restrict__ fcw,  const float* __restrict__ fcb,
    const float* __restrict__ pre,  float* __restrict__ out)
{
    __shared__ __align__(16) f16 wxl[Hn * WXS];    // 135168 B
    __shared__ __align__(16) f16 h1l[2][16 * HS];  //  16896 B
    __shared__ __align__(16) f16 h2l[16 * HS];     //   8448 B  (total 160512 <= 163840)

    const int tid  = threadIdx.x;
    const int lane = tid & 63, l15 = lane & 15, quad = lane >> 4;
    const int colbase = (tid >> 6) * 32;           // wave's 32-col slice

    // stage Wxh1: fp32 global -> f16 LDS (coalesced float4 reads)
    for (int i = tid; i < Hn * Hn / 4; i += 512) {
        int col = i >> 6, k4 = (i & 63) * 4;
        float4 v = *(const float4*)(Wxh1 + col * Hn + k4);
        f16x4 tv = { (f16)v.x, (f16)v.y, (f16)v.z, (f16)v.w };
        *(f16x4*)(&wxl[col * WXS + k4]) = tv;
    }
    for (int i = tid; i < 2 * 16 * HS; i += 512) ((f16*)h1l)[i] = (f16)0.0f;
    for (int i = tid; i < 16 * HS;     i += 512) h2l[i]         = (f16)0.0f;

    // register-resident weight fragments (B-operand) for Whh0, Whh1
    f16x8 wh0[2][8], wh1[2][8];
    float bi[2];
    #pragma unroll
    for (int jn = 0; jn < 2; jn++) {
        int col = colbase + jn * 16 + l15;
        bi[jn] = b1v[col];
        #pragma unroll
        for (int kk = 0; kk < 8; kk++) {
            #pragma unroll
            for (int j = 0; j < 8; j++) {
                wh0[jn][kk][j] = (f16)Whh0[col * Hn + kk * 32 + quad * 8 + j];
                wh1[jn][kk][j] = (f16)Whh1[col * Hn + kk * 32 + quad * 8 + j];
            }
        }
    }

    const int bg   = blockIdx.x * 16;
    const int prow = bg + quad * 4;
    float pA[8], pB[8];
    #pragma unroll
    for (int jn = 0; jn < 2; jn++)
        #pragma unroll
        for (int r = 0; r < 4; r++) {
            pA[jn*4+r] = pre[(size_t)(0 * Bsz + prow + r) * Hn + colbase + jn*16 + l15];
            pB[jn*4+r] = pre[(size_t)(1 * Bsz + prow + r) * Hn + colbase + jn*16 + l15];
        }
    __syncthreads();

#define FSTEP(SRC, DST, PR, TT) { \
    /* phase A: h1' = tanh(pre1[t] + h1 @ Whh0) ; pre as MFMA C-init */ \
    f32x4 accA[2]; \
    _Pragma("unroll") for (int jn = 0; jn < 2; jn++) \
        _Pragma("unroll") for (int r = 0; r < 4; r++) accA[jn][r] = PR[jn*4+r]; \
    _Pragma("unroll") for (int kk = 0; kk < 8; kk++) { \
        f16x8 a = *(const f16x8*)(&SRC[l15 * HS + kk * 32 + quad * 8]); \
        accA[0] = __builtin_amdgcn_mfma_f32_16x16x32_f16(a, wh0[0][kk], accA[0], 0, 0, 0); \
        accA[1] = __builtin_amdgcn_mfma_f32_16x16x32_f16(a, wh0[1][kk], accA[1], 0, 0, 0); \
    } \
    _Pragma("unroll") for (int jn = 0; jn < 2; jn++) \
        _Pragma("unroll") for (int r = 0; r < 4; r++) \
            DST[(quad*4+r) * HS + colbase + jn*16 + l15] = (f16)tanh_fast(accA[jn][r]); \
    { int tf = ((TT) + 2 < Tn) ? (TT) + 2 : Tn - 1; \
      _Pragma("unroll") for (int jn = 0; jn < 2; jn++) \
          _Pragma("unroll") for (int r = 0; r < 4; r++) \
              PR[jn*4+r] = pre[(size_t)(tf * Bsz + prow + r) * Hn + colbase + jn*16 + l15]; } \
    wg_barrier(); /* B1: h1' visible to all waves */ \
    /* phase BC: h2' = tanh(b1 + h1' @ Wxh1 + h2 @ Whh1) */ \
    f32x4 accX[2], accH[2]; \
    _Pragma("unroll") for (int jn = 0; jn < 2; jn++) \
        _Pragma("unroll") for (int r = 0; r < 4; r++) { accX[jn][r] = bi[jn]; accH[jn][r] = 0.f; } \
    _Pragma("unroll") for (int kk = 0; kk < 8; kk++) { \
        f16x8 a1  = *(const f16x8*)(&DST[l15 * HS + kk * 32 + quad * 8]); \
        f16x8 a2  = *(const f16x8*)(&h2l[l15 * HS + kk * 32 + quad * 8]); \
        f16x8 bx0 = *(const f16x8*)(&wxl[(colbase +  0 + l15) * WXS + kk * 32 + quad * 8]); \
        f16x8 bx1 = *(const f16x8*)(&wxl[(colbase + 16 + l15) * WXS + kk * 32 + quad * 8]); \
        accX[0] = __builtin_amdgcn_mfma_f32_16x16x32_f16(a1, bx0,        accX[0], 0, 0, 0); \
        accX[1] = __builtin_amdgcn_mfma_f32_16x16x32_f16(a1, bx1,        accX[1], 0, 0, 0); \
        accH[0] = __builtin_amdgcn_mfma_f32_16x16x32_f16(a2, wh1[0][kk], accH[0], 0, 0, 0); \
        accH[1] = __builtin_amdgcn_mfma_f32_16x16x32_f16(a2, wh1[1][kk], accH[1], 0, 0, 0); \
    } \
    wg_barrier(); /* B2: all reads of h2l complete before overwrite */ \
    _Pragma("unroll") for (int jn = 0; jn < 2; jn++) \
        _Pragma("unroll") for (int r = 0; r < 4; r++) \
            h2l[(quad*4+r) * HS + colbase + jn*16 + l15] = (f16)tanh_fast(accX[jn][r] + accH[jn][r]); \
    wg_barrier(); /* B3: h2' visible for next step */ \
}

    #pragma unroll 1
    for (int tp = 0; tp < Tn / 2; ++tp) {
        const int t0 = tp * 2;
        FSTEP(h1l[0], h1l[1], pA, t0)
        FSTEP(h1l[1], h1l[0], pB, (t0 + 1))
    }
#undef FSTEP

    // head: out[b][o] = h2[1023][b] . fc_w[o] + fc_b[o]  (h2l final, post-B3)
    if (tid < 256) {
        const int bl = tid >> 4, o = (tid >> 3) & 1, kc = tid & 7;
        float s = 0.f;
        #pragma unroll
        for (int k = 0; k < 32; k++)
            s += (float)h2l[bl * HS + kc * 32 + k] * fcw[o * Hn + kc * 32 + k];
        s += __shfl_down(s, 4);
        s += __shfl_down(s, 2);
        s += __shfl_down(s, 1);
        if (kc == 0)
            out[(bg + bl) * 2 + o] = s + fcb[o];
    }
}

extern "C" void kernel_launch(void* const* d_in, const int* in_sizes, int n_in,
                              void* d_out, int out_size, void* d_ws, size_t ws_size,
                              hipStream_t stream) {
    const float* x    = (const float*)d_in[0];
    const float* Wxh0 = (const float*)d_in[1];
    const float* Whh0 = (const float*)d_in[2];
    const float* b0   = (const float*)d_in[3];
    const float* Wxh1 = (const float*)d_in[4];
    const float* Whh1 = (const float*)d_in[5];
    const float* b1   = (const float*)d_in[6];
    const float* fcw  = (const float*)d_in[7];
    const float* fcb  = (const float*)d_in[8];
    float* out = (float*)d_out;

    float* pre = (float*)d_ws;  // [T][B][H] fp32 = 128 MiB

    k_xproj<<<dim3(Bsz * Tn / 64), dim3(256), 0, stream>>>(x, Wxh0, b0, pre);
    k_fused<<<dim3(Bsz / 16),      dim3(512), 0, stream>>>(Whh0, Wxh1, Whh1, b1,
                                                           fcw, fcb, pre, out);
}

// Round 6
// 1537.288 us; speedup vs baseline: 1.8596x; 1.4159x over previous
//
#include <hip/hip_runtime.h>

#define Bsz 128
#define Tn  1024
#define Dn  256
#define Hn  256

typedef _Float16 f16;
typedef _Float16 f16x4 __attribute__((ext_vector_type(4)));
typedef _Float16 f16x8 __attribute__((ext_vector_type(8)));
typedef float f32x4 __attribute__((ext_vector_type(4)));

// Exact tanh: 1 - 2/(e^{2x}+1) via v_exp_f32. err ~1e-6, saturates correctly.
__device__ __forceinline__ float tanh_fast(float x) {
    float e = __builtin_amdgcn_exp2f(x * 2.88539008177793f);  // e^{2x}
    return 1.0f - 2.0f * __builtin_amdgcn_rcpf(e + 1.0f);
}

// LDS-only barrier (lgkmcnt drain, no vmcnt) so global prefetch loads stay
// in flight across steps. All global loads are consumed by the issuing lane.
__device__ __forceinline__ void wg_barrier() {
    asm volatile("s_waitcnt lgkmcnt(0)\n\ts_barrier" ::: "memory");
}

// h fragment-major LDS layout: element (m=batch 0..15, k=0..255) lives at
// f16 offset (k>>5)*512 + ((k>>3)&3)*128 + m*8 + (k&7).
// A wave's B-fragment read for K-block kk is then ds_read_b128 at
// kk*1024B + lane*16B  -> stride-1 lane-contiguous, conflict-free.

// ---------------------------------------------------------------------------
// K1: pre_T[t][j][b] = x[b][t][:] . Wxh0[j][:] + b0[j]   (fp32 in/out)
// Transposed GEMM: A = Wxh0 (j rows, regs), B = x_t (b cols, LDS).
// grid = Tn WGs (one t each), 256 thr (4 waves x 64 j-cols).
// ---------------------------------------------------------------------------
__global__ __launch_bounds__(256, 2) void k_xproj(
    const float* __restrict__ x, const float* __restrict__ W,
    const float* __restrict__ bias, float* __restrict__ preT)
{
    __shared__ __align__(16) f16 xt[128][264];
    const int tid = threadIdx.x;
    const int t = blockIdx.x;

    // stage x[:, t, :] -> f16 LDS (row-major, padded)
    for (int i = tid; i < 128 * 64; i += 256) {
        int row = i >> 6, c4 = i & 63;
        float4 v = *(const float4*)(x + ((size_t)row * Tn + t) * Dn + c4 * 4);
        f16x4 tv = { (f16)v.x, (f16)v.y, (f16)v.z, (f16)v.w };
        *(f16x4*)(&xt[row][c4 * 4]) = tv;
    }

    const int lane = tid & 63, l15 = lane & 15, quad = lane >> 4;
    const int w = tid >> 6;

    // A-fragments of Wxh0 (j = w*64 + jn*16 + l15, k = kk*32 + quad*8 + e)
    f16x8 wf[4][8];
    #pragma unroll
    for (int jn = 0; jn < 4; jn++) {
        int j = w * 64 + jn * 16 + l15;
        #pragma unroll
        for (int kk = 0; kk < 8; kk++)
            #pragma unroll
            for (int e = 0; e < 8; e++)
                wf[jn][kk][e] = (f16)W[(size_t)j * Dn + kk * 32 + quad * 8 + e];
    }
    float4 bi[4];
    #pragma unroll
    for (int jn = 0; jn < 4; jn++)
        bi[jn] = *(const float4*)(bias + w * 64 + jn * 16 + quad * 4);

    __syncthreads();

    #pragma unroll 1
    for (int bblk = 0; bblk < 8; bblk++) {
        f32x4 acc[4];
        #pragma unroll
        for (int jn = 0; jn < 4; jn++)
            acc[jn] = (f32x4){bi[jn].x, bi[jn].y, bi[jn].z, bi[jn].w};
        #pragma unroll
        for (int kk = 0; kk < 8; kk++) {
            f16x8 xb = *(const f16x8*)(&xt[bblk * 16 + l15][kk * 32 + quad * 8]);
            #pragma unroll
            for (int jn = 0; jn < 4; jn++)
                acc[jn] = __builtin_amdgcn_mfma_f32_16x16x32_f16(wf[jn][kk], xb, acc[jn], 0, 0, 0);
        }
        // C-layout: lane holds rows j = w*64+jn*16+quad*4+r, col b = bblk*16+l15
        #pragma unroll
        for (int jn = 0; jn < 4; jn++)
            #pragma unroll
            for (int r = 0; r < 4; r++) {
                int j = w * 64 + jn * 16 + quad * 4 + r;
                preT[((size_t)t * Hn + j) * Bsz + bblk * 16 + l15] = acc[jn][r];
            }
    }
}

// ---------------------------------------------------------------------------
// K2 (fused, transposed): both recurrences + head. 8 WGs x 512 thr
// (8 waves x 32 j-cols, 2 waves/SIMD). All weights (Whh0, Wxh1, Whh1) as
// A-fragments in registers (~192 VGPR). h1/h2 double-buffered frag-major LDS.
//   per step t (P = t&1):
//     h1[1-P] = tanh(pre_T[t] + Whh0 . h1[P])        [A]
//     bar1
//     h2[1-P] = tanh(b1 + Wxh1 . h1[1-P] + Whh1 . h2[P])   [BC]
//     bar2
// ---------------------------------------------------------------------------
__global__ __launch_bounds__(512, 2) void k_fused(
    const float* __restrict__ Whh0, const float* __restrict__ Wxh1,
    const float* __restrict__ Whh1, const float* __restrict__ b1v,
    const float* __restrict__ fcw,  const float* __restrict__ fcb,
    const float* __restrict__ preT, float* __restrict__ out)
{
    __shared__ __align__(16) f16 h1f[2][4096];  // 8 KB each, frag-major
    __shared__ __align__(16) f16 h2f[2][4096];

    const int tid  = threadIdx.x;
    const int lane = tid & 63, l15 = lane & 15, quad = lane >> 4;
    const int w    = tid >> 6;
    const int colbase = w * 32;
    const int bg   = blockIdx.x * 16;

    for (int i = tid; i < 4096; i += 512) {
        h1f[0][i] = (f16)0.0f; h1f[1][i] = (f16)0.0f;
        h2f[0][i] = (f16)0.0f; h2f[1][i] = (f16)0.0f;
    }

    // A-fragments: row j = colbase + jn*16 + l15, k = kk*32 + quad*8 + e
    f16x8 wh0[2][8], wx[2][8], wh1[2][8];
    #pragma unroll
    for (int jn = 0; jn < 2; jn++) {
        int j = colbase + jn * 16 + l15;
        #pragma unroll
        for (int kk = 0; kk < 8; kk++)
            #pragma unroll
            for (int e = 0; e < 8; e++) {
                int o = (int)((size_t)j * Hn + kk * 32 + quad * 8 + e);
                wh0[jn][kk][e] = (f16)Whh0[o];
                wx [jn][kk][e] = (f16)Wxh1[o];
                wh1[jn][kk][e] = (f16)Whh1[o];
            }
    }
    float4 bi[2];
    #pragma unroll
    for (int jn = 0; jn < 2; jn++)
        bi[jn] = *(const float4*)(b1v + colbase + jn * 16 + quad * 4);

    // write offsets for the h epilogue (per jn): 4 consecutive k = n0..n0+3
    int wroff[2];
    #pragma unroll
    for (int jn = 0; jn < 2; jn++) {
        int n0 = colbase + jn * 16 + quad * 4;
        wroff[jn] = (n0 >> 5) * 512 + ((n0 >> 3) & 3) * 128 + l15 * 8 + (n0 & 7);
    }

    // pre prefetch (1 step ahead): lane value (jn,r) <-> pre_T[t][j][bg+l15]
    float pn[8];
    #pragma unroll
    for (int jn = 0; jn < 2; jn++)
        #pragma unroll
        for (int r = 0; r < 4; r++) {
            int j = colbase + jn * 16 + quad * 4 + r;
            pn[jn * 4 + r] = preT[((size_t)0 * Hn + j) * Bsz + bg + l15];
        }
    __syncthreads();

#define FSTEP(P, TT) { \
    /* phase A: h1' = tanh(pre + Whh0 . h1) */ \
    f32x4 accA[2]; \
    _Pragma("unroll") for (int jn = 0; jn < 2; jn++) \
        _Pragma("unroll") for (int r = 0; r < 4; r++) accA[jn][r] = pn[jn*4+r]; \
    { int tf = ((TT) + 1 < Tn) ? (TT) + 1 : Tn - 1; \
      _Pragma("unroll") for (int jn = 0; jn < 2; jn++) \
          _Pragma("unroll") for (int r = 0; r < 4; r++) { \
              int j = colbase + jn * 16 + quad * 4 + r; \
              pn[jn*4+r] = preT[((size_t)tf * Hn + j) * Bsz + bg + l15]; } } \
    _Pragma("unroll") for (int kk = 0; kk < 8; kk++) { \
        f16x8 hb = *(const f16x8*)(&h1f[P][kk * 512 + lane * 8]); \
        accA[0] = __builtin_amdgcn_mfma_f32_16x16x32_f16(wh0[0][kk], hb, accA[0], 0, 0, 0); \
        accA[1] = __builtin_amdgcn_mfma_f32_16x16x32_f16(wh0[1][kk], hb, accA[1], 0, 0, 0); \
    } \
    _Pragma("unroll") for (int jn = 0; jn < 2; jn++) { \
        f16x4 t4 = { (f16)tanh_fast(accA[jn][0]), (f16)tanh_fast(accA[jn][1]), \
                     (f16)tanh_fast(accA[jn][2]), (f16)tanh_fast(accA[jn][3]) }; \
        *(f16x4*)(&h1f[1-(P)][wroff[jn]]) = t4; \
    } \
    wg_barrier(); /* h1' visible */ \
    /* phase BC: h2' = tanh(b1 + Wxh1 . h1' + Whh1 . h2) */ \
    f32x4 accB[2]; \
    _Pragma("unroll") for (int jn = 0; jn < 2; jn++) \
        accB[jn] = (f32x4){bi[jn].x, bi[jn].y, bi[jn].z, bi[jn].w}; \
    _Pragma("unroll") for (int kk = 0; kk < 8; kk++) { \
        f16x8 h1b = *(const f16x8*)(&h1f[1-(P)][kk * 512 + lane * 8]); \
        f16x8 h2b = *(const f16x8*)(&h2f[P][kk * 512 + lane * 8]); \
        accB[0] = __builtin_amdgcn_mfma_f32_16x16x32_f16(wx [0][kk], h1b, accB[0], 0, 0, 0); \
        accB[1] = __builtin_amdgcn_mfma_f32_16x16x32_f16(wx [1][kk], h1b, accB[1], 0, 0, 0); \
        accB[0] = __builtin_amdgcn_mfma_f32_16x16x32_f16(wh1[0][kk], h2b, accB[0], 0, 0, 0); \
        accB[1] = __builtin_amdgcn_mfma_f32_16x16x32_f16(wh1[1][kk], h2b, accB[1], 0, 0, 0); \
    } \
    _Pragma("unroll") for (int jn = 0; jn < 2; jn++) { \
        f16x4 t4 = { (f16)tanh_fast(accB[jn][0]), (f16)tanh_fast(accB[jn][1]), \
                     (f16)tanh_fast(accB[jn][2]), (f16)tanh_fast(accB[jn][3]) }; \
        *(f16x4*)(&h2f[1-(P)][wroff[jn]]) = t4; \
    } \
    wg_barrier(); /* step complete */ \
}

    #pragma unroll 1
    for (int tp = 0; tp < Tn / 2; ++tp) {
        const int t0 = tp * 2;
        FSTEP(0, t0)
        FSTEP(1, (t0 + 1))
    }
#undef FSTEP

    // head: final h2 is in h2f[0] (t=1023, P=1, wrote h2f[0]); frag-major.
    if (tid < 256) {
        const int bl = tid >> 4, o = (tid >> 3) & 1, kc = tid & 7;
        float s = 0.f;
        #pragma unroll
        for (int kq = 0; kq < 32; kq++) {
            int k = kc * 32 + kq;
            f16 hv = h2f[0][(k >> 5) * 512 + ((k >> 3) & 3) * 128 + bl * 8 + (k & 7)];
            s += (float)hv * fcw[o * Hn + k];
        }
        s += __shfl_down(s, 4);
        s += __shfl_down(s, 2);
        s += __shfl_down(s, 1);
        if (kc == 0)
            out[(bg + bl) * 2 + o] = s + fcb[o];
    }
}

extern "C" void kernel_launch(void* const* d_in, const int* in_sizes, int n_in,
                              void* d_out, int out_size, void* d_ws, size_t ws_size,
                              hipStream_t stream) {
    const float* x    = (const float*)d_in[0];
    const float* Wxh0 = (const float*)d_in[1];
    const float* Whh0 = (const float*)d_in[2];
    const float* b0   = (const float*)d_in[3];
    const float* Wxh1 = (const float*)d_in[4];
    const float* Whh1 = (const float*)d_in[5];
    const float* b1   = (const float*)d_in[6];
    const float* fcw  = (const float*)d_in[7];
    const float* fcb  = (const float*)d_in[8];
    float* out = (float*)d_out;

    float* preT = (float*)d_ws;  // pre_T[t][j][b] fp32 = 128 MiB

    k_xproj<<<dim3(Tn),       dim3(256), 0, stream>>>(x, Wxh0, b0, preT);
    k_fused<<<dim3(Bsz / 16), dim3(512), 0, stream>>>(Whh0, Wxh1, Whh1, b1,
                                                      fcw, fcb, preT, out);
}